// Round 11
// baseline (213.916 us; speedup 1.0000x reference)
//
#include <hip/hip_runtime.h>
#include <hip/hip_bf16.h>

using bf16x4 = __attribute__((ext_vector_type(4))) short;
using short8 = __attribute__((ext_vector_type(8))) short;
using f32x4  = __attribute__((ext_vector_type(4))) float;
using u32x2  = __attribute__((ext_vector_type(2))) unsigned;

__device__ __forceinline__ short f2bf(float f) {
  unsigned u = __builtin_bit_cast(unsigned, f);
  u = (u + 0x7fffu + ((u >> 16) & 1u)) >> 16;  // RNE
  return (short)u;
}
__device__ __forceinline__ unsigned pk2(float a, float b) {
  __hip_bfloat162 h = __float22bfloat162_rn(make_float2(a, b));
  unsigned u; __builtin_memcpy(&u, &h, 4);
  return u;
}
__device__ __forceinline__ void gload16(const short* g, short* l) {
  __builtin_amdgcn_global_load_lds(
      (const __attribute__((address_space(1))) unsigned int*)g,
      (__attribute__((address_space(3))) unsigned int*)l, 16, 0, 0);
}

constexpr int E  = 1024;
constexpr int SL = 2048;
constexpr int NB = 2;
constexpr int NH = 16;
constexpr int M  = NB * SL;  // 4096

// fp32 -> bf16 one-shot convert: out = Xb(4M) | Wq(1M) | Wk(1M) | Wv(1M) | Wo(1M)
__global__ __launch_bounds__(256) void convert_kernel(
    const float* __restrict__ X,  const float* __restrict__ Wq,
    const float* __restrict__ Wk, const float* __restrict__ Wv,
    const float* __restrict__ Wo, short* __restrict__ out)
{
  const size_t i8 = ((size_t)blockIdx.x * 256 + threadIdx.x) * 8;
  const float* src;
  if (i8 < (size_t)(4u << 20)) {
    src = X + i8;
  } else {
    size_t r = i8 - (size_t)(4u << 20);
    int wi = (int)(r >> 20);
    size_t off = r & ((1u << 20) - 1);
    src = (wi == 0 ? Wq : wi == 1 ? Wk : wi == 2 ? Wv : Wo) + off;
  }
  f32x4 a = *(const f32x4*)src;
  f32x4 b = *(const f32x4*)(src + 4);
  short hb[8];
#pragma unroll
  for (int e = 0; e < 4; ++e) { hb[e] = f2bf(a[e]); hb[4 + e] = f2bf(b[e]); }
  *(short8*)(out + i8) = *(short8*)hb;
}

// Y[m,n] = (sum_k A[m,k]*W[n,k] + bias) * scale, bf16 in, fp32 accum.
// BK=32, double-buffered LDS, one barrier/iter (R10 structure).
// FUSEV && z==2: swapped block mapping + bias[m] (V^T slice).
template <int TM, int TN, bool OUTF32, bool FUSEV>
__global__ __launch_bounds__(256) void gemm_kernel(
    const short* __restrict__ A0, const short* __restrict__ A1, const short* __restrict__ A2,
    const short* __restrict__ W0, const short* __restrict__ W1, const short* __restrict__ W2,
    const float* __restrict__ b0, const float* __restrict__ b1, const float* __restrict__ b2,
    void* __restrict__ Y0, void* __restrict__ Y1, void* __restrict__ Y2,
    float s0, float s1, float s2, int ld0, int ld1, int ld2)
{
  constexpr int BK = 32;
  constexpr int RA = TM / 64;
  constexpr int RB = TN / 64;
  constexpr int WM = TM / 2, WN = TN / 2;
  constexpr int NI = WM / 16, NJ = WN / 16;
  __shared__ alignas(16) short As[2][TM * BK];
  __shared__ alignas(16) short Bs[2][TN * BK];
  const int t = threadIdx.x;
  const int l = t & 63;
  const int w = t >> 6;
  const int c = l & 15;
  const int g = l >> 4;
  const int z = blockIdx.z;
  const short* Ap = (z == 0) ? A0 : (z == 1) ? A1 : A2;
  const short* Wp = (z == 0) ? W0 : (z == 1) ? W1 : W2;
  const float* bp = (z == 0) ? b0 : (z == 1) ? b1 : b2;
  void* Yp        = (z == 0) ? Y0 : (z == 1) ? Y1 : Y2;
  const float sc  = (z == 0) ? s0 : (z == 1) ? s1 : s2;
  const int ldY   = (z == 0) ? ld0 : (z == 1) ? ld1 : ld2;
  const bool vtr  = FUSEV && (z == 2);
  const int m0 = (vtr ? blockIdx.y : blockIdx.x) * TM;
  const int n0 = (vtr ? blockIdx.x : blockIdx.y) * TN;

  const short* gA[RA]; int oA[RA];
  const short* gB[RB]; int oB[RB];
#pragma unroll
  for (int r = 0; r < RA; ++r) {
    const int cc = r * 256 + t;
    gA[r] = Ap + (size_t)(m0 + (cc >> 2)) * E + (cc & 3) * 8;
    oA[r] = (r * 256 + (t & ~63)) * 8;
  }
#pragma unroll
  for (int r = 0; r < RB; ++r) {
    const int cc = r * 256 + t;
    gB[r] = Wp + (size_t)(n0 + (cc >> 2)) * E + (cc & 3) * 8;
    oB[r] = (r * 256 + (t & ~63)) * 8;
  }

#pragma unroll
  for (int r = 0; r < RA; ++r) gload16(gA[r], &As[0][oA[r]]);
#pragma unroll
  for (int r = 0; r < RB; ++r) gload16(gB[r], &Bs[0][oB[r]]);

  const int wm = (w >> 1) * WM;
  const int wn = (w & 1) * WN;
  f32x4 acc[NI][NJ] = {};
  int cur = 0;

  for (int k0 = 0; k0 < E; k0 += BK) {
    __syncthreads();
    if (k0 + BK < E) {
#pragma unroll
      for (int r = 0; r < RA; ++r) gload16(gA[r] + k0 + BK, &As[cur ^ 1][oA[r]]);
#pragma unroll
      for (int r = 0; r < RB; ++r) gload16(gB[r] + k0 + BK, &Bs[cur ^ 1][oB[r]]);
    }
    short8 ah[NI], bfr[NJ];
#pragma unroll
    for (int i = 0; i < NI; ++i)
      ah[i] = *(const short8*)&As[cur][(wm + i * 16 + c) * BK + g * 8];
#pragma unroll
    for (int j = 0; j < NJ; ++j)
      bfr[j] = *(const short8*)&Bs[cur][(wn + j * 16 + c) * BK + g * 8];
#pragma unroll
    for (int i = 0; i < NI; ++i)
#pragma unroll
      for (int j = 0; j < NJ; ++j)
        acc[i][j] = __builtin_amdgcn_mfma_f32_16x16x32_bf16(ah[i], bfr[j], acc[i][j], 0, 0, 0);
    cur ^= 1;
  }

#pragma unroll
  for (int j = 0; j < NJ; ++j) {
    const int col = n0 + wn + j * 16 + c;
    const float bcol = vtr ? 0.f : bp[col];
#pragma unroll
    for (int i = 0; i < NI; ++i) {
      const int rowb = m0 + wm + i * 16 + g * 4;
#pragma unroll
      for (int r = 0; r < 4; ++r) {
        const int row = rowb + r;
        const float bias = vtr ? bp[row] : bcol;
        const float v = (acc[i][j][r] + bias) * sc;
        if (OUTF32) ((float*)Yp)[(size_t)row * ldY + col] = v;
        else        ((short*)Yp)[(size_t)row * ldY + col] = f2bf(v);
      }
    }
  }
}

// Flash, S^T formulation. 256 thr / 4 waves; q-tile 128 = 4 waves x 32 q
// (2 16-q subtiles per wave sharing the SAME K/V fragment reads -> LDS
// traffic per FLOP cut 0.64x; flash is LDS-BW-bound). LDS double-buffered
// K/V (one barrier per tile) + register prefetch of tile kt+1.
// Q pre-scaled by log2(e)/8 -> p = exp2(s).
__global__ __launch_bounds__(256) void flash_kernel(
    const short* __restrict__ Qm, const short* __restrict__ Km,
    const short* __restrict__ VTm, short* __restrict__ Oh)
{
  __shared__ alignas(16) short Ks[2][64][72];   // [buf][key][d]
  __shared__ alignas(16) short Vt[2][64][72];   // [buf][d][key]
  __shared__ alignas(16) short Pl[4][32][72];   // per-wave [q][key]
  const int t = threadIdx.x;
  const int l = t & 63;
  const int w = t >> 6;          // 0..3
  const int c = l & 15;
  const int g = l >> 4;
  const int q0 = blockIdx.x * 128;
  const int bh = (int)blockIdx.y;
  const int b = bh >> 4;
  const int hh = bh & 15;
  const size_t baseK = (size_t)b * SL * E + hh * 64;            // Q/K [token][feat]
  const size_t baseV = (size_t)(hh * 64) * M + (size_t)b * SL;  // V^T [feat][token]

  // Q B-frags for subtiles u=0,1: token = q0 + w*32 + u*16 + c
  short8 aq[2][2];
#pragma unroll
  for (int u = 0; u < 2; ++u) {
    const short* qp = Qm + baseK + (size_t)(q0 + w * 32 + u * 16 + c) * E + g * 8;
    aq[u][0] = *(const short8*)qp;
    aq[u][1] = *(const short8*)(qp + 32);
  }

  f32x4 lacc[2] = {{0.f,0.f,0.f,0.f},{0.f,0.f,0.f,0.f}};
  f32x4 acc_o[2][4] = {};

  // staging: thread covers rows r0=t>>3 and r0+32, seg t&7 (16B each)
  const int r0 = t >> 3, s0 = t & 7;
  const short* gK0 = Km + baseK + (size_t)r0 * E + s0 * 8;
  const short* gK1 = gK0 + (size_t)32 * E;
  const short* gV0 = VTm + baseV + (size_t)r0 * M + s0 * 8;
  const short* gV1 = gV0 + (size_t)32 * M;

  short8 k0r = *(const short8*)gK0, k1r = *(const short8*)gK1;
  short8 v0r = *(const short8*)gV0, v1r = *(const short8*)gV1;
  // write tile 0 -> buf 0
  *(short8*)&Ks[0][r0][s0 * 8]      = k0r;
  *(short8*)&Ks[0][r0 + 32][s0 * 8] = k1r;
  *(short8*)&Vt[0][r0][s0 * 8]      = v0r;
  *(short8*)&Vt[0][r0 + 32][s0 * 8] = v1r;
  // prefetch tile 1 -> regs
  k0r = *(const short8*)(gK0 + (size_t)64 * E);
  k1r = *(const short8*)(gK1 + (size_t)64 * E);
  v0r = *(const short8*)(gV0 + 64);
  v1r = *(const short8*)(gV1 + 64);
  __syncthreads();   // buf0 visible

  constexpr int NT = SL / 64;
  int cur = 0;
  for (int kt = 0; kt < NT; ++kt) {
    if (kt + 1 < NT) {
      // write tile kt+1 (in regs) into the other buffer; no barrier needed
      *(short8*)&Ks[cur ^ 1][r0][s0 * 8]      = k0r;
      *(short8*)&Ks[cur ^ 1][r0 + 32][s0 * 8] = k1r;
      *(short8*)&Vt[cur ^ 1][r0][s0 * 8]      = v0r;
      *(short8*)&Vt[cur ^ 1][r0 + 32][s0 * 8] = v1r;
      if (kt + 2 < NT) {
        k0r = *(const short8*)(gK0 + (size_t)(kt + 2) * 64 * E);
        k1r = *(const short8*)(gK1 + (size_t)(kt + 2) * 64 * E);
        v0r = *(const short8*)(gV0 + (kt + 2) * 64);
        v1r = *(const short8*)(gV1 + (kt + 2) * 64);
      }
    }

    // hoisted K-frags (shared by both q-subtiles)
    short8 kf[4][2];
#pragma unroll
    for (int j = 0; j < 4; ++j)
#pragma unroll
      for (int kc = 0; kc < 2; ++kc)
        kf[j][kc] = *(const short8*)&Ks[cur][j * 16 + c][kc * 32 + g * 8];

    // S^T[key][q] for both subtiles
    f32x4 st[2][4] = {};
#pragma unroll
    for (int u = 0; u < 2; ++u)
#pragma unroll
      for (int j = 0; j < 4; ++j)
#pragma unroll
        for (int kc = 0; kc < 2; ++kc)
          st[u][j] = __builtin_amdgcn_mfma_f32_16x16x32_bf16(kf[j][kc], aq[u][kc], st[u][j], 0, 0, 0);

    // p = 2^st; per-lane partial row sums; pack -> Pl
#pragma unroll
    for (int u = 0; u < 2; ++u)
#pragma unroll
      for (int j = 0; j < 4; ++j) {
        f32x4 p;
#pragma unroll
        for (int r = 0; r < 4; ++r) p[r] = __builtin_amdgcn_exp2f(st[u][j][r]);
        lacc[u] += p;
        u32x2 pk = {pk2(p[0], p[1]), pk2(p[2], p[3])};
        *(u32x2*)&Pl[w][u * 16 + c][j * 16 + g * 4] = pk;
      }

    // P B-frags (same-wave LDS RAW) + hoisted V-frags
    short8 ap[2][2];
#pragma unroll
    for (int u = 0; u < 2; ++u) {
      ap[u][0] = *(const short8*)&Pl[w][u * 16 + c][g * 8];
      ap[u][1] = *(const short8*)&Pl[w][u * 16 + c][32 + g * 8];
    }
    short8 vf[4][2];
#pragma unroll
    for (int j = 0; j < 4; ++j)
#pragma unroll
      for (int kc = 0; kc < 2; ++kc)
        vf[j][kc] = *(const short8*)&Vt[cur][j * 16 + c][kc * 32 + g * 8];

    // O^T[d][q] += V^T . P for both subtiles
#pragma unroll
    for (int u = 0; u < 2; ++u)
#pragma unroll
      for (int j = 0; j < 4; ++j)
#pragma unroll
        for (int kc = 0; kc < 2; ++kc)
          acc_o[u][j] = __builtin_amdgcn_mfma_f32_16x16x32_bf16(vf[j][kc], ap[u][kc], acc_o[u][j], 0, 0, 0);

    __syncthreads();   // buf[cur^1] visible; buf[cur] free for overwrite
    cur ^= 1;
  }

  // epilogue per subtile: row-sum across the 4 lanes holding q (xor 16,32)
#pragma unroll
  for (int u = 0; u < 2; ++u) {
    float s = lacc[u][0] + lacc[u][1] + lacc[u][2] + lacc[u][3];
    s += __shfl_xor(s, 16);
    s += __shfl_xor(s, 32);
    const float inv = 1.0f / s;
    const int token = q0 + w * 32 + u * 16 + c;
    const size_t obase = ((size_t)b * SL + token) * E + hh * 64;
#pragma unroll
    for (int j = 0; j < 4; ++j) {
      u32x2 o2 = {pk2(acc_o[u][j][0] * inv, acc_o[u][j][1] * inv),
                  pk2(acc_o[u][j][2] * inv, acc_o[u][j][3] * inv)};
      *(u32x2*)(Oh + obase + j * 16 + g * 4) = o2;
    }
  }
}

extern "C" void kernel_launch(void* const* d_in, const int* in_sizes, int n_in,
                              void* d_out, int out_size, void* d_ws, size_t ws_size,
                              hipStream_t stream)
{
  const float* X  = (const float*)d_in[0];
  const float* Wq = (const float*)d_in[1];
  const float* bq = (const float*)d_in[2];
  const float* Wk = (const float*)d_in[3];
  const float* bk = (const float*)d_in[4];
  const float* Wv = (const float*)d_in[5];
  const float* bv = (const float*)d_in[6];
  const float* Wo = (const float*)d_in[7];
  const float* bo = (const float*)d_in[8];
  float* out = (float*)d_out;

  const size_t szX = (size_t)M * E;       // 4M elems
  const size_t szW = (size_t)E * E;       // 1M elems
  short* Xb  = (short*)d_ws;
  short* Wqb = Xb + szX;
  short* Wkb = Wqb + szW;
  short* Wvb = Wkb + szW;
  short* Wob = Wvb + szW;
  short* Qw  = Wob + szW;                 // later reused as Oh
  short* Kw  = Qw + szX;
  short* VTw = Kw + szX;                  // [1024][4096]; total ws 40 MB

  convert_kernel<<<4096, 256, 0, stream>>>(X, Wq, Wk, Wv, Wo, Xb);

  // Fused projections: z0 Q (scaled log2e/8), z1 K, z2 V^T (swapped, bias[m])
  const float kLog2eOver8 = 0.18033688011112042f;
  dim3 g1(M / 128, E / 128, 3);
  gemm_kernel<128, 128, false, true><<<g1, 256, 0, stream>>>(
      Xb, Xb, Wvb,
      Wqb, Wkb, Xb,
      bq, bk, bv,
      (void*)Qw, (void*)Kw, (void*)VTw,
      kLog2eOver8, 1.0f, 1.0f, E, E, M);

  dim3 g2(SL / 128, NB * NH);
  flash_kernel<<<g2, 256, 0, stream>>>(Qw, Kw, VTw, Qw /*Oh in-place*/);

  // Final: out = Oh@Wo^T + bo, 128x64 tile (grid 512)
  dim3 g3(M / 128, E / 64, 1);
  gemm_kernel<128, 64, true, false><<<g3, 256, 0, stream>>>(
      Qw, Qw, Qw,
      Wob, Wob, Wob,
      bo, bo, bo,
      (void*)out, (void*)out, (void*)out,
      1.0f, 1.0f, 1.0f, E, E, E);
}

// Round 12
// 211.553 us; speedup vs baseline: 1.0112x; 1.0112x over previous
//
#include <hip/hip_runtime.h>
#include <hip/hip_bf16.h>

using bf16x4 = __attribute__((ext_vector_type(4))) short;
using short8 = __attribute__((ext_vector_type(8))) short;
using f32x4  = __attribute__((ext_vector_type(4))) float;
using u32x2  = __attribute__((ext_vector_type(2))) unsigned;

__device__ __forceinline__ short f2bf(float f) {
  unsigned u = __builtin_bit_cast(unsigned, f);
  u = (u + 0x7fffu + ((u >> 16) & 1u)) >> 16;  // RNE
  return (short)u;
}
__device__ __forceinline__ float bf2f(short s) {
  unsigned u = ((unsigned)(unsigned short)s) << 16;
  return __builtin_bit_cast(float, u);
}
__device__ __forceinline__ unsigned pk2(float a, float b) {
  __hip_bfloat162 h = __float22bfloat162_rn(make_float2(a, b));
  unsigned u; __builtin_memcpy(&u, &h, 4);
  return u;
}
__device__ __forceinline__ void gload16(const short* g, short* l) {
  __builtin_amdgcn_global_load_lds(
      (const __attribute__((address_space(1))) unsigned int*)g,
      (__attribute__((address_space(3))) unsigned int*)l, 16, 0, 0);
}

constexpr int E  = 1024;
constexpr int SL = 2048;
constexpr int NB = 2;
constexpr int NH = 16;
constexpr int M  = NB * SL;  // 4096
constexpr size_t MM = 1u << 20;  // 1M elements

// fp32 -> bf16 convert: contiguous Xb(4M)|Wq|Wk|Wv at `out`, Wo -> `outWo`.
__global__ __launch_bounds__(256) void convert_kernel(
    const float* __restrict__ X,  const float* __restrict__ Wq,
    const float* __restrict__ Wk, const float* __restrict__ Wv,
    const float* __restrict__ Wo, short* __restrict__ out,
    short* __restrict__ outWo)
{
  const size_t i8 = ((size_t)blockIdx.x * 256 + threadIdx.x) * 8;
  const float* src; short* dst;
  if (i8 < 4 * MM) {
    src = X + i8; dst = out + i8;
  } else {
    size_t r = i8 - 4 * MM;
    int wi = (int)(r >> 20);
    size_t off = r & (MM - 1);
    if      (wi == 0) { src = Wq + off; dst = out + 4 * MM + off; }
    else if (wi == 1) { src = Wk + off; dst = out + 5 * MM + off; }
    else if (wi == 2) { src = Wv + off; dst = out + 6 * MM + off; }
    else              { src = Wo + off; dst = outWo + off; }
  }
  f32x4 a = *(const f32x4*)src;
  f32x4 b = *(const f32x4*)(src + 4);
  short hb[8];
#pragma unroll
  for (int e = 0; e < 4; ++e) { hb[e] = f2bf(a[e]); hb[4 + e] = f2bf(b[e]); }
  *(short8*)dst = *(short8*)hb;
}

// Y[m,n] = (sum_k A[m,k]*W[n,k] + bias) * scale, bf16 in, fp32 accum.
// BK=32, double-buffered LDS, one barrier/iter (R10 structure).
// FUSEV && z==2: swapped block mapping + bias[m] (V^T slice).
template <int TM, int TN, bool OUTF32, bool FUSEV>
__global__ __launch_bounds__(256) void gemm_kernel(
    const short* __restrict__ A0, const short* __restrict__ A1, const short* __restrict__ A2,
    const short* __restrict__ W0, const short* __restrict__ W1, const short* __restrict__ W2,
    const float* __restrict__ b0, const float* __restrict__ b1, const float* __restrict__ b2,
    void* __restrict__ Y0, void* __restrict__ Y1, void* __restrict__ Y2,
    float s0, float s1, float s2, int ld0, int ld1, int ld2)
{
  constexpr int BK = 32;
  constexpr int RA = TM / 64;
  constexpr int RB = TN / 64;
  constexpr int WM = TM / 2, WN = TN / 2;
  constexpr int NI = WM / 16, NJ = WN / 16;
  __shared__ alignas(16) short As[2][TM * BK];
  __shared__ alignas(16) short Bs[2][TN * BK];
  const int t = threadIdx.x;
  const int l = t & 63;
  const int w = t >> 6;
  const int c = l & 15;
  const int g = l >> 4;
  const int z = blockIdx.z;
  const short* Ap = (z == 0) ? A0 : (z == 1) ? A1 : A2;
  const short* Wp = (z == 0) ? W0 : (z == 1) ? W1 : W2;
  const float* bp = (z == 0) ? b0 : (z == 1) ? b1 : b2;
  void* Yp        = (z == 0) ? Y0 : (z == 1) ? Y1 : Y2;
  const float sc  = (z == 0) ? s0 : (z == 1) ? s1 : s2;
  const int ldY   = (z == 0) ? ld0 : (z == 1) ? ld1 : ld2;
  const bool vtr  = FUSEV && (z == 2);
  const int m0 = (vtr ? blockIdx.y : blockIdx.x) * TM;
  const int n0 = (vtr ? blockIdx.x : blockIdx.y) * TN;

  const short* gA[RA]; int oA[RA];
  const short* gB[RB]; int oB[RB];
#pragma unroll
  for (int r = 0; r < RA; ++r) {
    const int cc = r * 256 + t;
    gA[r] = Ap + (size_t)(m0 + (cc >> 2)) * E + (cc & 3) * 8;
    oA[r] = (r * 256 + (t & ~63)) * 8;
  }
#pragma unroll
  for (int r = 0; r < RB; ++r) {
    const int cc = r * 256 + t;
    gB[r] = Wp + (size_t)(n0 + (cc >> 2)) * E + (cc & 3) * 8;
    oB[r] = (r * 256 + (t & ~63)) * 8;
  }

#pragma unroll
  for (int r = 0; r < RA; ++r) gload16(gA[r], &As[0][oA[r]]);
#pragma unroll
  for (int r = 0; r < RB; ++r) gload16(gB[r], &Bs[0][oB[r]]);

  const int wm = (w >> 1) * WM;
  const int wn = (w & 1) * WN;
  f32x4 acc[NI][NJ] = {};
  int cur = 0;

  for (int k0 = 0; k0 < E; k0 += BK) {
    __syncthreads();
    if (k0 + BK < E) {
#pragma unroll
      for (int r = 0; r < RA; ++r) gload16(gA[r] + k0 + BK, &As[cur ^ 1][oA[r]]);
#pragma unroll
      for (int r = 0; r < RB; ++r) gload16(gB[r] + k0 + BK, &Bs[cur ^ 1][oB[r]]);
    }
    short8 ah[NI], bfr[NJ];
#pragma unroll
    for (int i = 0; i < NI; ++i)
      ah[i] = *(const short8*)&As[cur][(wm + i * 16 + c) * BK + g * 8];
#pragma unroll
    for (int j = 0; j < NJ; ++j)
      bfr[j] = *(const short8*)&Bs[cur][(wn + j * 16 + c) * BK + g * 8];
#pragma unroll
    for (int i = 0; i < NI; ++i)
#pragma unroll
      for (int j = 0; j < NJ; ++j)
        acc[i][j] = __builtin_amdgcn_mfma_f32_16x16x32_bf16(ah[i], bfr[j], acc[i][j], 0, 0, 0);
    cur ^= 1;
  }

#pragma unroll
  for (int j = 0; j < NJ; ++j) {
    const int col = n0 + wn + j * 16 + c;
    const float bcol = vtr ? 0.f : bp[col];
#pragma unroll
    for (int i = 0; i < NI; ++i) {
      const int rowb = m0 + wm + i * 16 + g * 4;
#pragma unroll
      for (int r = 0; r < 4; ++r) {
        const int row = rowb + r;
        const float bias = vtr ? bp[row] : bcol;
        const float v = (acc[i][j][r] + bias) * sc;
        if (OUTF32) ((float*)Yp)[(size_t)row * ldY + col] = v;
        else        ((short*)Yp)[(size_t)row * ldY + col] = f2bf(v);
      }
    }
  }
}

// Split-K flash, S^T formulation. grid (SL/128, NB*NH, 2); 256 thr / 4 waves,
// each wave 32 q (2 subtiles sharing K/V frag reads). Each split ks handles 16
// of the 32 key-tiles and emits UNNORMALIZED bf16 O-partial + fp32 row-sum
// (exact: no-max softmax => O = (O1+O2)/(l1+l2)). 1024 blocks = 4/CU =
// 16 waves/CU (fixes R11's 8-waves/CU latency exposure) with 36.8 KB LDS.
// Q pre-scaled by log2(e)/8 -> p = exp2(s). Register prefetch of next tile.
__global__ __launch_bounds__(256, 4) void flash_kernel(
    const short* __restrict__ Qm, const short* __restrict__ Km,
    const short* __restrict__ VTm, short* __restrict__ O1,
    short* __restrict__ O2a, short* __restrict__ O2b,
    float* __restrict__ lpart)
{
  __shared__ alignas(16) short Ks[64][72];    // [key][d]
  __shared__ alignas(16) short Vt[64][72];    // [d][key]
  __shared__ alignas(16) short Pl[4][32][72]; // per-wave [q][key]
  const int t = threadIdx.x;
  const int l = t & 63;
  const int w = t >> 6;
  const int c = l & 15;
  const int g = l >> 4;
  const int q0 = blockIdx.x * 128;
  const int bh = (int)blockIdx.y;
  const int b = bh >> 4;
  const int hh = bh & 15;
  const int ks = (int)blockIdx.z;
  const size_t baseK = (size_t)b * SL * E + hh * 64;            // Q/K [token][feat]
  const size_t baseV = (size_t)(hh * 64) * M + (size_t)b * SL;  // V^T [feat][token]

  short8 aq[2][2];
#pragma unroll
  for (int u = 0; u < 2; ++u) {
    const short* qp = Qm + baseK + (size_t)(q0 + w * 32 + u * 16 + c) * E + g * 8;
    aq[u][0] = *(const short8*)qp;
    aq[u][1] = *(const short8*)(qp + 32);
  }

  f32x4 lacc[2] = {{0.f,0.f,0.f,0.f},{0.f,0.f,0.f,0.f}};
  f32x4 acc_o[2][4] = {};

  // staging: thread covers rows r0 and r0+32, 16B seg each
  const int r0 = t >> 3, sg = t & 7;
  const short* gK0 = Km + baseK + (size_t)(ks * 1024 + r0) * E + sg * 8;
  const short* gK1 = gK0 + (size_t)32 * E;
  const short* gV0 = VTm + baseV + (size_t)r0 * M + ks * 1024 + sg * 8;
  const short* gV1 = gV0 + (size_t)32 * M;

  short8 k0r = *(const short8*)gK0, k1r = *(const short8*)gK1;
  short8 v0r = *(const short8*)gV0, v1r = *(const short8*)gV1;

  for (int kt = 0; kt < 16; ++kt) {
    __syncthreads();                 // previous compute done reading LDS
    *(short8*)&Ks[r0][sg * 8]      = k0r;
    *(short8*)&Ks[r0 + 32][sg * 8] = k1r;
    *(short8*)&Vt[r0][sg * 8]      = v0r;
    *(short8*)&Vt[r0 + 32][sg * 8] = v1r;
    __syncthreads();
    if (kt + 1 < 16) {               // register prefetch of next tile
      k0r = *(const short8*)(gK0 + (size_t)(kt + 1) * 64 * E);
      k1r = *(const short8*)(gK1 + (size_t)(kt + 1) * 64 * E);
      v0r = *(const short8*)(gV0 + (kt + 1) * 64);
      v1r = *(const short8*)(gV1 + (kt + 1) * 64);
    }

    // hoisted K-frags shared by both q-subtiles
    short8 kf[4][2];
#pragma unroll
    for (int j = 0; j < 4; ++j)
#pragma unroll
      for (int kc = 0; kc < 2; ++kc)
        kf[j][kc] = *(const short8*)&Ks[j * 16 + c][kc * 32 + g * 8];

    f32x4 st[2][4] = {};
#pragma unroll
    for (int u = 0; u < 2; ++u)
#pragma unroll
      for (int j = 0; j < 4; ++j)
#pragma unroll
        for (int kc = 0; kc < 2; ++kc)
          st[u][j] = __builtin_amdgcn_mfma_f32_16x16x32_bf16(kf[j][kc], aq[u][kc], st[u][j], 0, 0, 0);

#pragma unroll
    for (int u = 0; u < 2; ++u)
#pragma unroll
      for (int j = 0; j < 4; ++j) {
        f32x4 p;
#pragma unroll
        for (int r = 0; r < 4; ++r) p[r] = __builtin_amdgcn_exp2f(st[u][j][r]);
        lacc[u] += p;
        u32x2 pk = {pk2(p[0], p[1]), pk2(p[2], p[3])};
        *(u32x2*)&Pl[w][u * 16 + c][j * 16 + g * 4] = pk;
      }

    short8 ap[2][2];
#pragma unroll
    for (int u = 0; u < 2; ++u) {
      ap[u][0] = *(const short8*)&Pl[w][u * 16 + c][g * 8];
      ap[u][1] = *(const short8*)&Pl[w][u * 16 + c][32 + g * 8];
    }
    short8 vf[4][2];
#pragma unroll
    for (int j = 0; j < 4; ++j)
#pragma unroll
      for (int kc = 0; kc < 2; ++kc)
        vf[j][kc] = *(const short8*)&Vt[j * 16 + c][kc * 32 + g * 8];

#pragma unroll
    for (int u = 0; u < 2; ++u)
#pragma unroll
      for (int j = 0; j < 4; ++j)
#pragma unroll
        for (int kc = 0; kc < 2; ++kc)
          acc_o[u][j] = __builtin_amdgcn_mfma_f32_16x16x32_bf16(vf[j][kc], ap[u][kc], acc_o[u][j], 0, 0, 0);
  }

  // epilogue: fold row-sum (lanes sharing q: xor 16,32); write UNNORMALIZED
  // O-partial (bf16) + l-partial (fp32, lane g==0)
#pragma unroll
  for (int u = 0; u < 2; ++u) {
    float s = lacc[u][0] + lacc[u][1] + lacc[u][2] + lacc[u][3];
    s += __shfl_xor(s, 16);
    s += __shfl_xor(s, 32);
    const int fr = b * SL + q0 + w * 32 + u * 16 + c;   // flat token row
    if (g == 0) lpart[(size_t)ks * 65536 + (size_t)fr * 16 + hh] = s;
    short* OB; size_t off;
    if (ks == 0)          { OB = O1;  off = (size_t)fr * E + hh * 64; }
    else if (fr < 3072)   { OB = O2a; off = (size_t)fr * E + hh * 64; }
    else                  { OB = O2b; off = (size_t)(fr - 3072) * E + hh * 64; }
#pragma unroll
    for (int j = 0; j < 4; ++j) {
      u32x2 o2 = {pk2(acc_o[u][j][0], acc_o[u][j][1]),
                  pk2(acc_o[u][j][2], acc_o[u][j][3])};
      *(u32x2*)(OB + off + j * 16 + g * 4) = o2;
    }
  }
}

// O = (O1+O2)/(l1+l2) -> bf16 Oh. 8 elems/thread (same head per group).
__global__ __launch_bounds__(256) void combine_kernel(
    const short* __restrict__ O1, const short* __restrict__ O2a,
    const short* __restrict__ O2b, const float* __restrict__ lpart,
    short* __restrict__ Oh)
{
  const size_t i8 = ((size_t)blockIdx.x * 256 + threadIdx.x) * 8;
  const size_t fr = i8 >> 10;
  const int h = (int)((i8 >> 6) & 15);
  const float linv = 1.0f / (lpart[fr * 16 + h] + lpart[65536 + fr * 16 + h]);
  short8 a = *(const short8*)(O1 + i8);
  short8 bb = (fr < 3072) ? *(const short8*)(O2a + i8)
                          : *(const short8*)(O2b + (i8 - (size_t)3072 * 1024));
  short hb[8];
#pragma unroll
  for (int e = 0; e < 8; ++e)
    hb[e] = f2bf((bf2f(a[e]) + bf2f(bb[e])) * linv);
  *(short8*)(Oh + i8) = *(short8*)hb;
}

extern "C" void kernel_launch(void* const* d_in, const int* in_sizes, int n_in,
                              void* d_out, int out_size, void* d_ws, size_t ws_size,
                              hipStream_t stream)
{
  const float* X  = (const float*)d_in[0];
  const float* Wq = (const float*)d_in[1];
  const float* bq = (const float*)d_in[2];
  const float* Wk = (const float*)d_in[3];
  const float* bk = (const float*)d_in[4];
  const float* Wv = (const float*)d_in[5];
  const float* bv = (const float*)d_in[6];
  const float* Wo = (const float*)d_in[7];
  const float* bo = (const float*)d_in[8];
  float* out = (float*)d_out;

  // layout (bf16 elems): Xb 4M | Wq 1M | Wk 1M | Wv 1M | Qw 4M | Kw 4M |
  //                      VTw 4M | Wob 1M | lpart 128K fp32 | O2b 1M
  // overlays during/after flash: O1 -> Xb (dead), O2a -> Wq..Wv (dead, 3M rows 0..3071)
  short* Xb   = (short*)d_ws;
  short* Wqb  = Xb + 4 * MM;
  short* Wkb  = Wqb + MM;
  short* Wvb  = Wkb + MM;
  short* Qw   = Wvb + MM;
  short* Kw   = Qw + 4 * MM;
  short* VTw  = Kw + 4 * MM;
  short* Wob  = VTw + 4 * MM;
  float* lpart = (float*)(Wob + MM);
  short* O2b  = (short*)(lpart + 131072);   // total ws use: 42.5 MB
  short* O1   = Xb;
  short* O2a  = Wqb;

  convert_kernel<<<4096, 256, 0, stream>>>(X, Wq, Wk, Wv, Wo, Xb, Wob);

  // Fused projections: z0 Q (scaled log2e/8), z1 K, z2 V^T (swapped, bias[m])
  const float kLog2eOver8 = 0.18033688011112042f;
  dim3 g1(M / 128, E / 128, 3);
  gemm_kernel<128, 128, false, true><<<g1, 256, 0, stream>>>(
      Xb, Xb, Wvb,
      Wqb, Wkb, Xb,
      bq, bk, bv,
      (void*)Qw, (void*)Kw, (void*)VTw,
      kLog2eOver8, 1.0f, 1.0f, E, E, M);

  dim3 g2(SL / 128, NB * NH, 2);
  flash_kernel<<<g2, 256, 0, stream>>>(Qw, Kw, VTw, O1, O2a, O2b, lpart);

  combine_kernel<<<(M * E / 8) / 256, 256, 0, stream>>>(O1, O2a, O2b, lpart, Qw);

  // Final: out = Oh@Wo^T + bo, 128x64 tile (grid 512)
  dim3 g3(M / 128, E / 64, 1);
  gemm_kernel<128, 64, true, false><<<g3, 256, 0, stream>>>(
      Qw, Qw, Qw,
      Wob, Wob, Wob,
      bo, bo, bo,
      (void*)out, (void*)out, (void*)out,
      1.0f, 1.0f, 1.0f, E, E, E);
}